// Round 3
// baseline (385.783 us; speedup 1.0000x reference)
//
#include <hip/hip_runtime.h>
#include <math.h>

namespace {

constexpr int kB   = 64;
constexpr int kCin = 8;
constexpr int kR   = 800;
constexpr int kNC  = 128;
constexpr int kO   = 16;
constexpr int TPB  = 1024;
constexpr int NITER = 3;

// Phase-1 staging: 800 rows x 36 floats (b0 s at +0..15, b1 at +16..31, pad).
// 36*4=144 B row stride -> every row float4-aligned. 115.2 KB (gfx950 LDS/CU
// is 160 KB; >64 KB static verified working in R2 at 69.6 KB).
constexpr int SROW = 36;
// Phase-2 reduction overlays the dead staging buffer.
// red: 256 rows x 35 | red2: 16 rows x 35 | shs: 34 (+pad to float4 align)
constexpr int RSTRIDE = 35;

__global__ __launch_bounds__(TPB, 4) void caps_route(
    const float* __restrict__ x, const float* __restrict__ W,
    float* __restrict__ out) {
  __shared__ float lds[kR * SROW];              // 115.2 KB
  float* const red  = lds;                      // 256 x 35
  float* const red2 = lds + 256 * RSTRIDE;      // 16 x 35
  float* const shs  = lds + 272 * RSTRIDE;      // 9520 floats in -> 16B aligned

  const int tid = threadIdx.x;

  // XCD swizzle: 32 blocks sharing c -> one XCD; W[c] (409.6 KB) L2-resident.
  const int j   = blockIdx.x;
  const int xcd = j & 7;
  const int k   = j >> 3;
  const int c   = ((k >> 5) << 3) + xcd;
  const int bg  = k & 31;
  const int b0  = bg * 2, b1 = b0 + 1;

  const float* Wc  = W + (size_t)c * kR * kCin * kO;
  const float* x0p = x + (size_t)b0 * kCin * kR;
  const float* x1p = x + (size_t)b1 * kCin * kR;

  // ---------------- Phase 1: priors into LDS staging ----------------
  // Unit (r, oc): 4 lanes w/ consecutive oc consume one full 64B W line.
  const int oc  = tid & 3;
  const int rl0 = tid >> 2;                     // 0..255
  for (int s = 0; s < 4; ++s) {
    const int r = s * 256 + rl0;
    if (r < kR) {
      float xv0[kCin], xv1[kCin];
      #pragma unroll
      for (int i = 0; i < kCin; ++i) {
        xv0[i] = x0p[i * kR + r];
        xv1[i] = x1p[i * kR + r];
      }
      const float4* Wr = reinterpret_cast<const float4*>(Wc + (size_t)r * kCin * kO);
      float4 a0 = make_float4(0.f, 0.f, 0.f, 0.f);
      float4 a1 = make_float4(0.f, 0.f, 0.f, 0.f);
      #pragma unroll
      for (int i = 0; i < kCin; ++i) {
        const float4 w = Wr[i * 4 + oc];
        a0.x += xv0[i] * w.x; a0.y += xv0[i] * w.y;
        a0.z += xv0[i] * w.z; a0.w += xv0[i] * w.w;
        a1.x += xv1[i] * w.x; a1.y += xv1[i] * w.y;
        a1.z += xv1[i] * w.z; a1.w += xv1[i] * w.w;
      }
      float4* st = reinterpret_cast<float4*>(lds + r * SROW);
      st[oc]     = a0;                          // b0 cols oc*4..oc*4+3
      st[4 + oc] = a1;                          // b1 cols 16+oc*4..
    }
  }
  __syncthreads();

  // Pickup: thread t owns row t of both b's (32 floats, registers).
  const bool act = (tid < kR);
  float P0[kO], P1[kO];
  if (act) {
    const float4* ld = reinterpret_cast<const float4*>(lds + tid * SROW);
    #pragma unroll
    for (int q = 0; q < 4; ++q) {
      const float4 v0 = ld[q];
      const float4 v1 = ld[4 + q];
      P0[q * 4 + 0] = v0.x; P0[q * 4 + 1] = v0.y;
      P0[q * 4 + 2] = v0.z; P0[q * 4 + 3] = v0.w;
      P1[q * 4 + 0] = v1.x; P1[q * 4 + 1] = v1.y;
      P1[q * 4 + 2] = v1.z; P1[q * 4 + 3] = v1.w;
    }
  }
  __syncthreads();   // staging dead; red region reusable

  // ---------------- Phase 2: routing, b0+b1 fused ----------------
  // col layout in red/shs: [0..15]=s(b0), [16..31]=s(b1), [32]=Z0, [33]=Z1.
  // No max-subtraction: logits bounded (~|delta|<15/iter), exp safe in fp32.
  const int grp = tid >> 2;                     // reduction row 0..255
  float l0 = 0.f, l1 = 0.f;

  #pragma unroll
  for (int it = 0; it < NITER; ++it) {
    // -- per-thread partials, 4-lane shuffle fold, write red row --
    {
      float sp[kO + 1];
      #pragma unroll
      for (int v = 0; v <= kO; ++v) sp[v] = 0.f;
      if (act) {
        const float e = (it == 0) ? 1.f : __expf(l0);
        sp[kO] = e;
        #pragma unroll
        for (int o = 0; o < kO; ++o) sp[o] = e * P0[o];
      }
      #pragma unroll
      for (int v = 0; v <= kO; ++v) {
        sp[v] += __shfl_xor(sp[v], 1, 64);
        sp[v] += __shfl_xor(sp[v], 2, 64);
      }
      if ((tid & 3) == 0) {
        #pragma unroll
        for (int o = 0; o < kO; ++o) red[grp * RSTRIDE + o] = sp[o];
        red[grp * RSTRIDE + 32] = sp[kO];
      }
    }
    {
      float sp[kO + 1];
      #pragma unroll
      for (int v = 0; v <= kO; ++v) sp[v] = 0.f;
      if (act) {
        const float e = (it == 0) ? 1.f : __expf(l1);
        sp[kO] = e;
        #pragma unroll
        for (int o = 0; o < kO; ++o) sp[o] = e * P1[o];
      }
      #pragma unroll
      for (int v = 0; v <= kO; ++v) {
        sp[v] += __shfl_xor(sp[v], 1, 64);
        sp[v] += __shfl_xor(sp[v], 2, 64);
      }
      if ((tid & 3) == 0) {
        #pragma unroll
        for (int o = 0; o < kO; ++o) red[grp * RSTRIDE + 16 + o] = sp[o];
        red[grp * RSTRIDE + 33] = sp[kO];
      }
    }
    __syncthreads();

    // -- tree: 256 rows -> 16 rows (544 threads) -> 1 row (34 threads) --
    if (tid < 544) {
      const int q = tid / 34, col = tid - q * 34;
      float a = 0.f;
      #pragma unroll
      for (int rr = 0; rr < 16; ++rr) a += red[(q * 16 + rr) * RSTRIDE + col];
      red2[q * RSTRIDE + col] = a;
    }
    __syncthreads();
    if (tid < 34) {
      float a = 0.f;
      #pragma unroll
      for (int q = 0; q < 16; ++q) a += red2[q * RSTRIDE + tid];
      shs[tid] = a;
    }
    __syncthreads();

    // -- squash (redundant per thread; sv never materialized) --
    const float4* sv4 = reinterpret_cast<const float4*>(shs);
    const float4 u0 = sv4[0], u1 = sv4[1], u2 = sv4[2], u3 = sv4[3]; // s(b0)
    const float4 w0 = sv4[4], w1 = sv4[5], w2 = sv4[6], w3 = sv4[7]; // s(b1)
    const float Zi0 = 1.f / shs[32];
    const float Zi1 = 1.f / shs[33];
    const float ss0 = u0.x*u0.x+u0.y*u0.y+u0.z*u0.z+u0.w*u0.w
                    + u1.x*u1.x+u1.y*u1.y+u1.z*u1.z+u1.w*u1.w
                    + u2.x*u2.x+u2.y*u2.y+u2.z*u2.z+u2.w*u2.w
                    + u3.x*u3.x+u3.y*u3.y+u3.z*u3.z+u3.w*u3.w;
    const float ss1 = w0.x*w0.x+w0.y*w0.y+w0.z*w0.z+w0.w*w0.w
                    + w1.x*w1.x+w1.y*w1.y+w1.z*w1.z+w1.w*w1.w
                    + w2.x*w2.x+w2.y*w2.y+w2.z*w2.z+w2.w*w2.w
                    + w3.x*w3.x+w3.y*w3.y+w3.z*w3.z+w3.w*w3.w;
    const float sn0 = ss0 * Zi0 * Zi0;
    const float sn1 = ss1 * Zi1 * Zi1;
    const float g0  = Zi0 * sqrtf(sn0) / (1.f + sn0);  // out/delta scale b0
    const float g1  = Zi1 * sqrtf(sn1) / (1.f + sn1);

    if (it < NITER - 1) {
      if (act) {
        float d0 = P0[0]*u0.x + P0[1]*u0.y + P0[2]*u0.z + P0[3]*u0.w
                 + P0[4]*u1.x + P0[5]*u1.y + P0[6]*u1.z + P0[7]*u1.w
                 + P0[8]*u2.x + P0[9]*u2.y + P0[10]*u2.z + P0[11]*u2.w
                 + P0[12]*u3.x + P0[13]*u3.y + P0[14]*u3.z + P0[15]*u3.w;
        float d1 = P1[0]*w0.x + P1[1]*w0.y + P1[2]*w0.z + P1[3]*w0.w
                 + P1[4]*w1.x + P1[5]*w1.y + P1[6]*w1.z + P1[7]*w1.w
                 + P1[8]*w2.x + P1[9]*w2.y + P1[10]*w2.z + P1[11]*w2.w
                 + P1[12]*w3.x + P1[13]*w3.y + P1[14]*w3.z + P1[15]*w3.w;
        l0 += d0 * g0;
        l1 += d1 * g1;
      }
    } else {
      // out[b, o, c], shape [B, O, NC]; shs[tid] is s0[tid] / s1[tid-16].
      if (tid < kO) {
        out[(size_t)b0 * kO * kNC + tid * kNC + c] = shs[tid] * g0;
      } else if (tid < 2 * kO) {
        out[(size_t)b1 * kO * kNC + (tid - kO) * kNC + c] = shs[tid] * g1;
      }
    }
  }
}

}  // namespace

extern "C" void kernel_launch(void* const* d_in, const int* in_sizes, int n_in,
                              void* d_out, int out_size, void* d_ws, size_t ws_size,
                              hipStream_t stream) {
  const float* x = (const float*)d_in[0];          // [64, 8, 800] fp32
  const float* W = (const float*)d_in[1];          // [128, 800, 8, 16] fp32
  float* out = (float*)d_out;                      // [64, 16, 128] fp32
  (void)in_sizes; (void)n_in; (void)out_size; (void)d_ws; (void)ws_size;
  const int grid = kNC * (kB / 2);                 // 4096 blocks: (c, b-pair)
  caps_route<<<dim3(grid), dim3(TPB), 0, stream>>>(x, W, out);
}

// Round 4
// 248.496 us; speedup vs baseline: 1.5525x; 1.5525x over previous
//
#include <hip/hip_runtime.h>
#include <math.h>

namespace {

constexpr int kB   = 64;
constexpr int kCin = 8;
constexpr int kR   = 800;
constexpr int kNC  = 128;
constexpr int kO   = 16;
constexpr int CT   = 256;   // conversion kernel TPB
constexpr int MT   = 512;   // main kernel TPB
constexpr int NITER = 3;
constexpr size_t WS_NEEDED =
    (size_t)kNC * kO * kR * kCin * sizeof(unsigned short);  // 26,214,400 B

__device__ __forceinline__ unsigned int f2bf(float f) {
  // round-to-nearest-even fp32 -> bf16
  unsigned int u = __float_as_uint(f);
  return (u + 0x7fffu + ((u >> 16) & 1u)) >> 16;
}

// ---------------- W conversion: fp32 [c][r][i][o] -> bf16 [c][o][r][i] -----
// Per-XCD working set of W drops to 16 c x 204.8 KB = 3.3 MB < 4 MB L2.
__global__ __launch_bounds__(CT) void conv_w(const float* __restrict__ W,
                                             unsigned short* __restrict__ Wb) {
  __shared__ float tile[32 * 132];   // 32 r-rows x 128 (+4 pad: float4-aligned,
                                     // read stride 132 -> conflict-free gather)
  const int blk = blockIdx.x;        // c*25 + rt
  const int c  = blk / 25;
  const int rt = blk - c * 25;
  const int r0 = rt * 32;
  const int t  = threadIdx.x;

  const float4* src =
      reinterpret_cast<const float4*>(W + ((size_t)c * kR + r0) * kCin * kO);
  #pragma unroll
  for (int k2 = 0; k2 < 4; ++k2) {
    const int i4  = t + k2 * CT;         // 0..1023 float4s, coalesced
    const float4 v = src[i4];
    const int fi = i4 * 4, row = fi >> 7, pos = fi & 127;
    float* d = &tile[row * 132 + pos];
    d[0] = v.x; d[1] = v.y; d[2] = v.z; d[3] = v.w;
  }
  __syncthreads();
  #pragma unroll
  for (int k2 = 0; k2 < 2; ++k2) {
    const int u  = t * 2 + k2;           // 0..511 output chunks (o, r_local)
    const int o  = u >> 5, rl = u & 31;
    unsigned int pk[4];
    #pragma unroll
    for (int q = 0; q < 4; ++q) {
      const unsigned int lo = f2bf(tile[rl * 132 + (2 * q + 0) * 16 + o]);
      const unsigned int hi = f2bf(tile[rl * 132 + (2 * q + 1) * 16 + o]);
      pk[q] = lo | (hi << 16);
    }
    // chunk id = (c*16+o)*800 + r ; 16B coalesced within each o-group
    uint4* dst = reinterpret_cast<uint4*>(Wb) +
                 ((size_t)(c * kO + o) * kR + (r0 + rl));
    *dst = make_uint4(pk[0], pk[1], pk[2], pk[3]);
  }
}

// ---------------- main: priors in registers + fused routing ----------------
template <bool BF16W>
__global__ __launch_bounds__(MT, 4) void caps_route(
    const float* __restrict__ x, const float* __restrict__ W,
    const unsigned short* __restrict__ Wb, float* __restrict__ out) {
  constexpr int RST = 19;               // 17 cols + pad (16*19 % 32 == 16: free)
  __shared__ float red[128 * RST];      // 9.5 KB
  __shared__ float red2[8 * RST];
  __shared__ float shs[20];

  const int t = threadIdx.x;
  // XCD swizzle: consecutive resident blocks on one XCD share c.
  const int j   = blockIdx.x;
  const int xcd = j & 7;
  const int k   = j >> 3;               // 0..1023
  const int c   = ((k >> 6) << 3) + xcd;
  const int b   = k & 63;

  const float* xb  = x + (size_t)b * kCin * kR;
  const bool  has2 = (t < kR - MT);     // t < 288 owns second row r2
  const int   r1   = t, r2 = MT + t;

  float P1[kO], P2[kO];

  // -------- Phase 1: priors straight into registers (no LDS, no barrier) ---
  {
    float xa[kCin];
    #pragma unroll
    for (int i = 0; i < kCin; ++i) xa[i] = xb[i * kR + r1];
    if (BF16W) {
      const uint4* Wc = reinterpret_cast<const uint4*>(Wb) + (size_t)c * kO * kR;
      #pragma unroll
      for (int o = 0; o < kO; ++o) {
        const uint4 w = Wc[(size_t)o * kR + r1];   // 16B coalesced, L2-hit
        const unsigned int wq[4] = {w.x, w.y, w.z, w.w};
        float acc = 0.f;
        #pragma unroll
        for (int q = 0; q < 4; ++q) {
          const float f0 = __uint_as_float(wq[q] << 16);
          const float f1 = __uint_as_float(wq[q] & 0xffff0000u);
          acc += xa[2 * q] * f0 + xa[2 * q + 1] * f1;
        }
        P1[o] = acc;
      }
    } else {
      const float* Wc = W + ((size_t)c * kR + r1) * kCin * kO;
      #pragma unroll
      for (int o = 0; o < kO; ++o) {
        float acc = 0.f;
        #pragma unroll
        for (int i = 0; i < kCin; ++i) acc += xa[i] * Wc[i * kO + o];
        P1[o] = acc;
      }
    }
  }
  if (has2) {
    float xa[kCin];
    #pragma unroll
    for (int i = 0; i < kCin; ++i) xa[i] = xb[i * kR + r2];
    if (BF16W) {
      const uint4* Wc = reinterpret_cast<const uint4*>(Wb) + (size_t)c * kO * kR;
      #pragma unroll
      for (int o = 0; o < kO; ++o) {
        const uint4 w = Wc[(size_t)o * kR + r2];
        const unsigned int wq[4] = {w.x, w.y, w.z, w.w};
        float acc = 0.f;
        #pragma unroll
        for (int q = 0; q < 4; ++q) {
          const float f0 = __uint_as_float(wq[q] << 16);
          const float f1 = __uint_as_float(wq[q] & 0xffff0000u);
          acc += xa[2 * q] * f0 + xa[2 * q + 1] * f1;
        }
        P2[o] = acc;
      }
    } else {
      const float* Wc = W + ((size_t)c * kR + r2) * kCin * kO;
      #pragma unroll
      for (int o = 0; o < kO; ++o) {
        float acc = 0.f;
        #pragma unroll
        for (int i = 0; i < kCin; ++i) acc += xa[i] * Wc[i * kO + o];
        P2[o] = acc;
      }
    }
  } else {
    #pragma unroll
    for (int o = 0; o < kO; ++o) P2[o] = 0.f;
  }

  // -------- Phase 2: 3 routing iterations ----------------------------------
  // No max-subtraction: logits start at 0, |delta| small -> exp safe in fp32.
  float l1 = 0.f, l2 = 0.f;
  #pragma unroll
  for (int it = 0; it < NITER; ++it) {
    const float e1 = (it == 0) ? 1.f : __expf(l1);
    const float e2 = has2 ? ((it == 0) ? 1.f : __expf(l2)) : 0.f;

    float sp[kO + 1];
    sp[kO] = e1 + e2;
    #pragma unroll
    for (int o = 0; o < kO; ++o) sp[o] = e1 * P1[o] + e2 * P2[o];

    // fold 4 lanes -> 1 row, 128 rows total
    #pragma unroll
    for (int v = 0; v <= kO; ++v) {
      sp[v] += __shfl_xor(sp[v], 1, 64);
      sp[v] += __shfl_xor(sp[v], 2, 64);
    }
    if ((t & 3) == 0) {
      const int row = t >> 2;
      #pragma unroll
      for (int v = 0; v <= kO; ++v) red[row * RST + v] = sp[v];
    }
    __syncthreads();

    if (t < 136) {                       // 8 q-groups x 17 cols
      const int q = t / 17, col = t - q * 17;
      float a = 0.f;
      #pragma unroll
      for (int rr = 0; rr < 16; ++rr) a += red[(q * 16 + rr) * RST + col];
      red2[q * RST + col] = a;
    }
    __syncthreads();
    if (t < 17) {
      float a = 0.f;
      #pragma unroll
      for (int q = 0; q < 8; ++q) a += red2[q * RST + t];
      shs[t] = a;
    }
    __syncthreads();

    // squash, redundantly per thread: v[o] = shs[o] * g
    const float Zi = 1.f / shs[kO];
    float ss = 0.f;
    #pragma unroll
    for (int o = 0; o < kO; ++o) ss += shs[o] * shs[o];
    const float sn = ss * Zi * Zi;
    const float g  = Zi * sqrtf(sn) / (1.f + sn);

    if (it < NITER - 1) {
      float d1 = 0.f, d2 = 0.f;
      #pragma unroll
      for (int o = 0; o < kO; ++o) {
        d1 += P1[o] * shs[o];
        d2 += P2[o] * shs[o];
      }
      l1 += d1 * g;
      if (has2) l2 += d2 * g;
    } else {
      if (t < kO) out[(size_t)b * kO * kNC + t * kNC + c] = shs[t] * g;
    }
  }
}

}  // namespace

extern "C" void kernel_launch(void* const* d_in, const int* in_sizes, int n_in,
                              void* d_out, int out_size, void* d_ws, size_t ws_size,
                              hipStream_t stream) {
  const float* x = (const float*)d_in[0];   // [64, 8, 800] fp32
  const float* W = (const float*)d_in[1];   // [128, 800, 8, 16] fp32
  float* out = (float*)d_out;               // [64, 16, 128] fp32
  (void)in_sizes; (void)n_in; (void)out_size;

  const int grid = kNC * kB;                // 8192 blocks: (c, b)
  if (ws_size >= WS_NEEDED) {
    unsigned short* Wb = (unsigned short*)d_ws;
    conv_w<<<dim3(kNC * 25), dim3(CT), 0, stream>>>(W, Wb);
    caps_route<true><<<dim3(grid), dim3(MT), 0, stream>>>(x, W, Wb, out);
  } else {
    caps_route<false><<<dim3(grid), dim3(MT), 0, stream>>>(x, W, nullptr, out);
  }
}